// Round 32
// baseline (61.839 us; speedup 1.0000x reference)
//
#include <hip/hip_runtime.h>
#include <hip/hip_bf16.h>

// Problem dims (fixed by reference)
#define N_IN   1024     // K
#define N_P    1024     // N (= 32*32 lifted grid)
#define FILT   33
#define PAD    16

typedef __attribute__((ext_vector_type(8))) __bf16 bf16x8;
typedef __attribute__((ext_vector_type(4))) float  f32x4;

#define GLB(p) ((const __attribute__((address_space(1))) unsigned int*)(p))
#define LDSP(p) ((__attribute__((address_space(3))) unsigned int*)(p))

__device__ __forceinline__ unsigned short f2bf(float f) {
    union { __hip_bfloat16 h; unsigned short u; } cv;
    cv.h = __float2bfloat16(f);
    return cv.u;
}

// ---------------------------------------------------------------------------
// Kernel 1: FUSED prep — normalize (blocks [0, M/4)) + filter-conv (rest).
// r20-proven; ~16.3 us ≈ its HBM floor (102 MB / 6.3 TB/s).
// ---------------------------------------------------------------------------
__global__ __launch_bounds__(256)
void prep_kernel(const float* __restrict__ x, __hip_bfloat16* __restrict__ xn,
                 const float* __restrict__ lm_raw, __hip_bfloat16* __restrict__ lm,
                 int norm_blocks)
{
    __shared__ float rowbuf[N_IN];
    __shared__ float fw[FILT];
    const int tid = threadIdx.x;

    if (blockIdx.x < norm_blocks) {
        const int lane = tid & 63;
        const int row  = blockIdx.x * 4 + (tid >> 6);

        const float4* xr = reinterpret_cast<const float4*>(x + (size_t)row * N_IN);
        float4 v[4];
        float s = 0.f, s2 = 0.f;
#pragma unroll
        for (int i = 0; i < 4; i++) {
            v[i] = xr[i * 64 + lane];
            s  += v[i].x + v[i].y + v[i].z + v[i].w;
            s2 += v[i].x * v[i].x + v[i].y * v[i].y + v[i].z * v[i].z + v[i].w * v[i].w;
        }
#pragma unroll
        for (int off = 32; off > 0; off >>= 1) {
            s  += __shfl_xor(s,  off, 64);
            s2 += __shfl_xor(s2, off, 64);
        }
        const float mu  = s * (1.0f / N_IN);
        const float var = fmaxf(s2 * (1.0f / N_IN) - mu * mu, 0.0f);
        const float inv = 1.0f / (sqrtf(var) + 1e-7f);

        ushort4* outv = reinterpret_cast<ushort4*>(xn + (size_t)row * N_IN);
#pragma unroll
        for (int i = 0; i < 4; i++) {
            ushort4 o;
            o.x = f2bf((v[i].x - mu) * inv);
            o.y = f2bf((v[i].y - mu) * inv);
            o.z = f2bf((v[i].z - mu) * inv);
            o.w = f2bf((v[i].w - mu) * inv);
            outv[i * 64 + lane] = o;
        }
    } else {
        const int p = blockIdx.x - norm_blocks;

        if (tid < FILT) {
            float t = (tid - PAD) * (2.0f / FILT);
            float u = t * 10.0f;            // t / sigma0 (sigma0 = 0.1)
            fw[tid] = expf(-0.5f * u * u);
        }
        reinterpret_cast<float4*>(rowbuf)[tid] =
            reinterpret_cast<const float4*>(lm_raw + (size_t)p * N_IN)[tid];
        __syncthreads();

        float fsum = 0.f;
#pragma unroll
        for (int f = 0; f < FILT; f++) fsum += fw[f];
        const float inv = 1.0f / fsum;

        const int n0 = tid * 4;
        float o[4] = {0.f, 0.f, 0.f, 0.f};
#pragma unroll
        for (int f = 0; f < FILT; f++) {
            const float w = fw[f];
#pragma unroll
            for (int j = 0; j < 4; j++)
                o[j] += w * rowbuf[(n0 + j + f - PAD) & (N_IN - 1)];
        }
        ushort4 ov;
        ov.x = f2bf(o[0] * inv);
        ov.y = f2bf(o[1] * inv);
        ov.z = f2bf(o[2] * inv);
        ov.w = f2bf(o[3] * inv);
        reinterpret_cast<ushort4*>(lm + (size_t)p * N_IN)[tid] = ov;
    }
}

// ---------------------------------------------------------------------------
// Kernel 2: GEMM  C[M,N] = A[M,K] * B[N,K]^T — FINAL session configuration
// (r29: paired-tile, gate-first, read-shadow stage, all-reads-upfront).
// 256x256 tile, BK=32, 512 thr (8 waves 2Mx4N), wave 128x64, acc[8][4],
// ring-4, one barrier per 2 K-tiles, swizzle key=(row>>1)&3 both sides,
// T1 bijective XCD swizzle, setprio around MFMA clusters, scalar epilogue.
// Per half-pair: gate vmcnt(4) -> ALL 12 ds_reads (bfr, afr, afr2) ->
// STAGE (4 gloads in read shadow) -> MFMA cluster m0-3 -> cluster m4-7
// (afr2 aged under cluster-1 via compiler's fine-grained lgkm).
// Ledger: pair-top {t,t+1}=8, gate t = vmcnt(4); after STAGE(t+2):
// {t+1,t+2}=8, gate t+1 = vmcnt(4) (vmcnt(0) final pair). Buffer safety:
// stages write (t-2)&3/(t-1)&3 after the pair-top barrier, whose
// lgkm(0)+barrier prove all waves consumed those tiles.
//
// SESSION LEDGER (16 GEMM variants, 76.99 -> 61.55 us total, -20%): wins =
// counted-vmcnt ring (55.8->45.4), 2-blk residency (43.3), pairing+split
// staging (41.2), gate-first+all-reads-upfront (39.8); prep fusion +1us.
// Refuted: fused-A, B-in-reg, 8-phase BK64, 2-phase template,
// async-redundant, 4-wave low-traffic, coalesced epilogues (x2),
// top-staged pair, B-prefetch (neutral). Plateau, not HW roofline:
// MfmaUtil ~33%, in-loop HBM 29%, conflicts 0, C-tail + prep at BW floor;
// residual is ds_read->MFMA latency granularity beyond this plain-HIP
// schedule space (consistent with guide's HIP-source vs hand-asm gap).
// ---------------------------------------------------------------------------
__global__ __launch_bounds__(512, 2)
void gemm_pair(const __hip_bfloat16* __restrict__ A,
               const __hip_bfloat16* __restrict__ B,
               float* __restrict__ C,
               int M, int N, int K)
{
    constexpr int BK = 32;                  // K-tile; rows are 64B (4 x 16B slots)
    __shared__ char smem[4][32768];         // ring-4: A[256][64B] @0 | B[256][64B] @16384

    const int tid = threadIdx.x;
    const int l   = tid & 63;
    const int w   = tid >> 6;    // 0..7
    const int wm  = w >> 2;      // 0..1  (M direction, 128 rows each)
    const int wn  = w & 3;       // 0..3  (N direction, 64 cols each)

    // T1: bijective XCD swizzle (nwg=256 divisible by 8)
    const int o    = blockIdx.x;
    const int lin  = (o & 7) * (gridDim.x >> 3) + (o >> 3);
    const int tn   = lin & 3;          // N/256 = 4
    const int tm   = lin >> 2;         // M/256 = 64
    const size_t bm = (size_t)tm * 256;
    const size_t bn = (size_t)tn * 256;

    // ---- staging geometry (per-lane global source, pre-swizzled) ----
    const int srow = w * 16 + (l >> 2);
    const int scol = 16 * ((l & 3) ^ ((l >> 3) & 3));
    const char* gA = (const char*)(A + (bm + srow) * (size_t)K) + scol;
    const char* gB = (const char*)(B + (bn + srow) * (size_t)K) + scol;
    const size_t rowstep = (size_t)128 * K * 2;     // +128 rows (bytes)

#define STAGE(t, b) do {                                                        \
    const char* a0_ = gA + (size_t)(t) * (BK * 2);                              \
    const char* b0_ = gB + (size_t)(t) * (BK * 2);                              \
    char* La_ = &smem[(b)][0]     + w * 1024;                                   \
    char* Lb_ = &smem[(b)][16384] + w * 1024;                                   \
    __builtin_amdgcn_global_load_lds(GLB(a0_),           LDSP(La_),        16, 0, 0); \
    __builtin_amdgcn_global_load_lds(GLB(a0_ + rowstep), LDSP(La_ + 8192), 16, 0, 0); \
    __builtin_amdgcn_global_load_lds(GLB(b0_),           LDSP(Lb_),        16, 0, 0); \
    __builtin_amdgcn_global_load_lds(GLB(b0_ + rowstep), LDSP(Lb_ + 8192), 16, 0, 0); \
} while (0)

    // one K-tile: ALL 12 reads -> stage (in read shadow) -> 2 MFMA clusters
#define COMPPAIR(b, dostage, st) do {                                           \
    const char* Sb_ = &smem[(b)][0];                                            \
    bf16x8 bfr[4], afr[4], afr2[4];                                             \
    _Pragma("unroll")                                                           \
    for (int n = 0; n < 4; n++) bfr[n]  = *(const bf16x8*)(Sb_ + bbase + n * 1024); \
    _Pragma("unroll")                                                           \
    for (int m = 0; m < 4; m++) afr[m]  = *(const bf16x8*)(Sb_ + abase + m * 1024); \
    _Pragma("unroll")                                                           \
    for (int m = 0; m < 4; m++) afr2[m] = *(const bf16x8*)(Sb_ + abase + (m + 4) * 1024); \
    if (dostage) STAGE(st, (st) & 3);                                           \
    __builtin_amdgcn_s_setprio(1);                                              \
    _Pragma("unroll")                                                           \
    for (int m = 0; m < 4; m++)                                                 \
        _Pragma("unroll")                                                       \
        for (int n = 0; n < 4; n++)                                             \
            acc[m][n] = __builtin_amdgcn_mfma_f32_16x16x32_bf16(afr[m], bfr[n], acc[m][n], 0, 0, 0); \
    __builtin_amdgcn_s_setprio(0);                                              \
    __builtin_amdgcn_s_setprio(1);                                              \
    _Pragma("unroll")                                                           \
    for (int m = 0; m < 4; m++)                                                 \
        _Pragma("unroll")                                                       \
        for (int n = 0; n < 4; n++)                                             \
            acc[m + 4][n] = __builtin_amdgcn_mfma_f32_16x16x32_bf16(afr2[m], bfr[n], acc[m + 4][n], 0, 0, 0); \
    __builtin_amdgcn_s_setprio(0);                                              \
} while (0)

    // ---- fragment-read geometry (swizzled ds_read, same involution) ----
    const int lr = l & 15;
    const int kb = l >> 4;                               // k-block of 8 elems
    const int rslot = 16 * (kb ^ ((lr >> 1) & 3));
    const int abase = (wm * 128 + lr) * 64 + rslot;          // + m*1024
    const int bbase = 16384 + (wn * 64 + lr) * 64 + rslot;   // + n*1024

    f32x4 acc[8][4] = {};
    const int NT = K / BK;                               // 32 (even)

    STAGE(0, 0);
    STAGE(1, 1);

    for (int t = 0; t < NT; t += 2) {
        // ---- pair-top: reads of tiles <= t-1 are consumed by every wave ----
        asm volatile("s_waitcnt lgkmcnt(0)" ::: "memory");
        __builtin_amdgcn_s_barrier();
        asm volatile("" ::: "memory");       // nothing hoists above the barrier
        __builtin_amdgcn_sched_barrier(0);

        // gate tile t: outstanding {t:4, t+1:4}; vmcnt(4) retires t
        asm volatile("s_waitcnt vmcnt(4)" ::: "memory");
        COMPPAIR(t & 3, t + 2 < NT, t + 2);

        // gate tile t+1: outstanding {t+1:4, t+2?:4}; vmcnt(4) retires t+1
        if (t + 2 < NT) asm volatile("s_waitcnt vmcnt(4)" ::: "memory");
        else            asm volatile("s_waitcnt vmcnt(0)" ::: "memory");
        COMPPAIR((t + 1) & 3, t + 3 < NT, t + 3);
    }
#undef STAGE
#undef COMPPAIR

    // epilogue: C/D layout col = lane&15, row = (lane>>4)*4 + reg  [m89/m91]
    const int crow = (l >> 4) * 4;
    const int ccol = l & 15;
#pragma unroll
    for (int m = 0; m < 8; m++)
#pragma unroll
        for (int n = 0; n < 4; n++) {
#pragma unroll
            for (int r = 0; r < 4; r++) {
                const size_t row = bm + wm * 128 + m * 16 + crow + r;
                const size_t col = bn + wn * 64 + n * 16 + ccol;
                C[row * N + col] = acc[m][n][r];
            }
        }
}

// ---------------------------------------------------------------------------
extern "C" void kernel_launch(void* const* d_in, const int* in_sizes, int n_in,
                              void* d_out, int out_size, void* d_ws, size_t ws_size,
                              hipStream_t stream) {
    const float* x      = (const float*)d_in[0];   // [M, 1024] fp32
    const float* lm_raw = (const float*)d_in[1];   // [32, 32, 1024] fp32
    float* out = (float*)d_out;                    // [M, 32, 32] fp32

    const int M = in_sizes[0] / N_IN;              // 16384

    // workspace layout: xn bf16 [M,1024] (32 MiB) | lm bf16 [1024,1024] (2 MiB)
    __hip_bfloat16* xn = (__hip_bfloat16*)d_ws;
    __hip_bfloat16* lm = (__hip_bfloat16*)((char*)d_ws + (size_t)M * N_IN * 2);

    const int norm_blocks = M / 4;                 // 4096
    prep_kernel<<<norm_blocks + N_P, 256, 0, stream>>>(x, xn, lm_raw, lm, norm_blocks);

    const int nblk = (M / 256) * (N_P / 256);      // 64 * 4 = 256
    gemm_pair<<<nblk, dim3(512), 0, stream>>>(xn, lm, out, M, N_P, N_IN);
}

// Round 33
// 61.541 us; speedup vs baseline: 1.0048x; 1.0048x over previous
//
#include <hip/hip_runtime.h>
#include <hip/hip_bf16.h>

// Problem dims (fixed by reference)
#define N_IN   1024     // K
#define N_P    1024     // N (= 32*32 lifted grid)
#define FILT   33
#define PAD    16

typedef __attribute__((ext_vector_type(8))) __bf16 bf16x8;
typedef __attribute__((ext_vector_type(4))) float  f32x4;

#define GLB(p) ((const __attribute__((address_space(1))) unsigned int*)(p))
#define LDSP(p) ((__attribute__((address_space(3))) unsigned int*)(p))

__device__ __forceinline__ unsigned short f2bf(float f) {
    union { __hip_bfloat16 h; unsigned short u; } cv;
    cv.h = __float2bfloat16(f);
    return cv.u;
}

// ---------------------------------------------------------------------------
// Kernel 1: FUSED prep — normalize (blocks [0, M/4)) + filter-conv (rest).
// r20-proven; ~16.3 us ≈ its HBM floor (102 MB / 6.3 TB/s).
// ---------------------------------------------------------------------------
__global__ __launch_bounds__(256)
void prep_kernel(const float* __restrict__ x, __hip_bfloat16* __restrict__ xn,
                 const float* __restrict__ lm_raw, __hip_bfloat16* __restrict__ lm,
                 int norm_blocks)
{
    __shared__ float rowbuf[N_IN];
    __shared__ float fw[FILT];
    const int tid = threadIdx.x;

    if (blockIdx.x < norm_blocks) {
        const int lane = tid & 63;
        const int row  = blockIdx.x * 4 + (tid >> 6);

        const float4* xr = reinterpret_cast<const float4*>(x + (size_t)row * N_IN);
        float4 v[4];
        float s = 0.f, s2 = 0.f;
#pragma unroll
        for (int i = 0; i < 4; i++) {
            v[i] = xr[i * 64 + lane];
            s  += v[i].x + v[i].y + v[i].z + v[i].w;
            s2 += v[i].x * v[i].x + v[i].y * v[i].y + v[i].z * v[i].z + v[i].w * v[i].w;
        }
#pragma unroll
        for (int off = 32; off > 0; off >>= 1) {
            s  += __shfl_xor(s,  off, 64);
            s2 += __shfl_xor(s2, off, 64);
        }
        const float mu  = s * (1.0f / N_IN);
        const float var = fmaxf(s2 * (1.0f / N_IN) - mu * mu, 0.0f);
        const float inv = 1.0f / (sqrtf(var) + 1e-7f);

        ushort4* outv = reinterpret_cast<ushort4*>(xn + (size_t)row * N_IN);
#pragma unroll
        for (int i = 0; i < 4; i++) {
            ushort4 o;
            o.x = f2bf((v[i].x - mu) * inv);
            o.y = f2bf((v[i].y - mu) * inv);
            o.z = f2bf((v[i].z - mu) * inv);
            o.w = f2bf((v[i].w - mu) * inv);
            outv[i * 64 + lane] = o;
        }
    } else {
        const int p = blockIdx.x - norm_blocks;

        if (tid < FILT) {
            float t = (tid - PAD) * (2.0f / FILT);
            float u = t * 10.0f;            // t / sigma0 (sigma0 = 0.1)
            fw[tid] = expf(-0.5f * u * u);
        }
        reinterpret_cast<float4*>(rowbuf)[tid] =
            reinterpret_cast<const float4*>(lm_raw + (size_t)p * N_IN)[tid];
        __syncthreads();

        float fsum = 0.f;
#pragma unroll
        for (int f = 0; f < FILT; f++) fsum += fw[f];
        const float inv = 1.0f / fsum;

        const int n0 = tid * 4;
        float o[4] = {0.f, 0.f, 0.f, 0.f};
#pragma unroll
        for (int f = 0; f < FILT; f++) {
            const float w = fw[f];
#pragma unroll
            for (int j = 0; j < 4; j++)
                o[j] += w * rowbuf[(n0 + j + f - PAD) & (N_IN - 1)];
        }
        ushort4 ov;
        ov.x = f2bf(o[0] * inv);
        ov.y = f2bf(o[1] * inv);
        ov.z = f2bf(o[2] * inv);
        ov.w = f2bf(o[3] * inv);
        reinterpret_cast<ushort4*>(lm + (size_t)p * N_IN)[tid] = ov;
    }
}

// ---------------------------------------------------------------------------
// Kernel 2: GEMM  C[M,N] = A[M,K] * B[N,K]^T — FINAL session configuration
// (r29: paired-tile, gate-first, read-shadow stage, all-reads-upfront).
// 256x256 tile, BK=32, 512 thr (8 waves 2Mx4N), wave 128x64, acc[8][4],
// ring-4, one barrier per 2 K-tiles, swizzle key=(row>>1)&3 both sides,
// T1 bijective XCD swizzle, setprio around MFMA clusters, scalar epilogue.
// Per half-pair: gate vmcnt(4) -> ALL 12 ds_reads (bfr, afr, afr2) ->
// STAGE (4 gloads in read shadow) -> MFMA cluster m0-3 -> cluster m4-7
// (afr2 aged under cluster-1 via compiler's fine-grained lgkm).
// Ledger: pair-top {t,t+1}=8, gate t = vmcnt(4); after STAGE(t+2):
// {t+1,t+2}=8, gate t+1 = vmcnt(4) (vmcnt(0) final pair). Buffer safety:
// stages write (t-2)&3/(t-1)&3 after the pair-top barrier, whose
// lgkm(0)+barrier prove all waves consumed those tiles.
//
// SESSION LEDGER (16 GEMM variants, 76.99 -> 61.55 us total, -20%,
// 4x reproduced): wins = counted-vmcnt ring (55.8->45.4), 2-blk residency
// (43.3), pairing+split staging (41.2), gate-first+all-reads-upfront (39.8);
// prep fusion +1us. Refuted: fused-A, B-in-reg, 8-phase BK64, 2-phase
// template, async-redundant, 4-wave low-traffic, coalesced epilogues (x2),
// top-staged pair, B-prefetch (neutral). Plateau, not HW roofline:
// MfmaUtil ~33%, in-loop HBM 29%, conflicts 0, C-tail + prep at BW floor;
// residual is ds_read->MFMA latency granularity beyond this plain-HIP
// schedule space (consistent with guide's HIP-source vs hand-asm gap).
// ---------------------------------------------------------------------------
__global__ __launch_bounds__(512, 2)
void gemm_pair(const __hip_bfloat16* __restrict__ A,
               const __hip_bfloat16* __restrict__ B,
               float* __restrict__ C,
               int M, int N, int K)
{
    constexpr int BK = 32;                  // K-tile; rows are 64B (4 x 16B slots)
    __shared__ char smem[4][32768];         // ring-4: A[256][64B] @0 | B[256][64B] @16384

    const int tid = threadIdx.x;
    const int l   = tid & 63;
    const int w   = tid >> 6;    // 0..7
    const int wm  = w >> 2;      // 0..1  (M direction, 128 rows each)
    const int wn  = w & 3;       // 0..3  (N direction, 64 cols each)

    // T1: bijective XCD swizzle (nwg=256 divisible by 8)
    const int o    = blockIdx.x;
    const int lin  = (o & 7) * (gridDim.x >> 3) + (o >> 3);
    const int tn   = lin & 3;          // N/256 = 4
    const int tm   = lin >> 2;         // M/256 = 64
    const size_t bm = (size_t)tm * 256;
    const size_t bn = (size_t)tn * 256;

    // ---- staging geometry (per-lane global source, pre-swizzled) ----
    const int srow = w * 16 + (l >> 2);
    const int scol = 16 * ((l & 3) ^ ((l >> 3) & 3));
    const char* gA = (const char*)(A + (bm + srow) * (size_t)K) + scol;
    const char* gB = (const char*)(B + (bn + srow) * (size_t)K) + scol;
    const size_t rowstep = (size_t)128 * K * 2;     // +128 rows (bytes)

#define STAGE(t, b) do {                                                        \
    const char* a0_ = gA + (size_t)(t) * (BK * 2);                              \
    const char* b0_ = gB + (size_t)(t) * (BK * 2);                              \
    char* La_ = &smem[(b)][0]     + w * 1024;                                   \
    char* Lb_ = &smem[(b)][16384] + w * 1024;                                   \
    __builtin_amdgcn_global_load_lds(GLB(a0_),           LDSP(La_),        16, 0, 0); \
    __builtin_amdgcn_global_load_lds(GLB(a0_ + rowstep), LDSP(La_ + 8192), 16, 0, 0); \
    __builtin_amdgcn_global_load_lds(GLB(b0_),           LDSP(Lb_),        16, 0, 0); \
    __builtin_amdgcn_global_load_lds(GLB(b0_ + rowstep), LDSP(Lb_ + 8192), 16, 0, 0); \
} while (0)

    // one K-tile: ALL 12 reads -> stage (in read shadow) -> 2 MFMA clusters
#define COMPPAIR(b, dostage, st) do {                                           \
    const char* Sb_ = &smem[(b)][0];                                            \
    bf16x8 bfr[4], afr[4], afr2[4];                                             \
    _Pragma("unroll")                                                           \
    for (int n = 0; n < 4; n++) bfr[n]  = *(const bf16x8*)(Sb_ + bbase + n * 1024); \
    _Pragma("unroll")                                                           \
    for (int m = 0; m < 4; m++) afr[m]  = *(const bf16x8*)(Sb_ + abase + m * 1024); \
    _Pragma("unroll")                                                           \
    for (int m = 0; m < 4; m++) afr2[m] = *(const bf16x8*)(Sb_ + abase + (m + 4) * 1024); \
    if (dostage) STAGE(st, (st) & 3);                                           \
    __builtin_amdgcn_s_setprio(1);                                              \
    _Pragma("unroll")                                                           \
    for (int m = 0; m < 4; m++)                                                 \
        _Pragma("unroll")                                                       \
        for (int n = 0; n < 4; n++)                                             \
            acc[m][n] = __builtin_amdgcn_mfma_f32_16x16x32_bf16(afr[m], bfr[n], acc[m][n], 0, 0, 0); \
    __builtin_amdgcn_s_setprio(0);                                              \
    __builtin_amdgcn_s_setprio(1);                                              \
    _Pragma("unroll")                                                           \
    for (int m = 0; m < 4; m++)                                                 \
        _Pragma("unroll")                                                       \
        for (int n = 0; n < 4; n++)                                             \
            acc[m + 4][n] = __builtin_amdgcn_mfma_f32_16x16x32_bf16(afr2[m], bfr[n], acc[m + 4][n], 0, 0, 0); \
    __builtin_amdgcn_s_setprio(0);                                              \
} while (0)

    // ---- fragment-read geometry (swizzled ds_read, same involution) ----
    const int lr = l & 15;
    const int kb = l >> 4;                               // k-block of 8 elems
    const int rslot = 16 * (kb ^ ((lr >> 1) & 3));
    const int abase = (wm * 128 + lr) * 64 + rslot;          // + m*1024
    const int bbase = 16384 + (wn * 64 + lr) * 64 + rslot;   // + n*1024

    f32x4 acc[8][4] = {};
    const int NT = K / BK;                               // 32 (even)

    STAGE(0, 0);
    STAGE(1, 1);

    for (int t = 0; t < NT; t += 2) {
        // ---- pair-top: reads of tiles <= t-1 are consumed by every wave ----
        asm volatile("s_waitcnt lgkmcnt(0)" ::: "memory");
        __builtin_amdgcn_s_barrier();
        asm volatile("" ::: "memory");       // nothing hoists above the barrier
        __builtin_amdgcn_sched_barrier(0);

        // gate tile t: outstanding {t:4, t+1:4}; vmcnt(4) retires t
        asm volatile("s_waitcnt vmcnt(4)" ::: "memory");
        COMPPAIR(t & 3, t + 2 < NT, t + 2);

        // gate tile t+1: outstanding {t+1:4, t+2?:4}; vmcnt(4) retires t+1
        if (t + 2 < NT) asm volatile("s_waitcnt vmcnt(4)" ::: "memory");
        else            asm volatile("s_waitcnt vmcnt(0)" ::: "memory");
        COMPPAIR((t + 1) & 3, t + 3 < NT, t + 3);
    }
#undef STAGE
#undef COMPPAIR

    // epilogue: C/D layout col = lane&15, row = (lane>>4)*4 + reg  [m89/m91]
    const int crow = (l >> 4) * 4;
    const int ccol = l & 15;
#pragma unroll
    for (int m = 0; m < 8; m++)
#pragma unroll
        for (int n = 0; n < 4; n++) {
#pragma unroll
            for (int r = 0; r < 4; r++) {
                const size_t row = bm + wm * 128 + m * 16 + crow + r;
                const size_t col = bn + wn * 64 + n * 16 + ccol;
                C[row * N + col] = acc[m][n][r];
            }
        }
}

// ---------------------------------------------------------------------------
extern "C" void kernel_launch(void* const* d_in, const int* in_sizes, int n_in,
                              void* d_out, int out_size, void* d_ws, size_t ws_size,
                              hipStream_t stream) {
    const float* x      = (const float*)d_in[0];   // [M, 1024] fp32
    const float* lm_raw = (const float*)d_in[1];   // [32, 32, 1024] fp32
    float* out = (float*)d_out;                    // [M, 32, 32] fp32

    const int M = in_sizes[0] / N_IN;              // 16384

    // workspace layout: xn bf16 [M,1024] (32 MiB) | lm bf16 [1024,1024] (2 MiB)
    __hip_bfloat16* xn = (__hip_bfloat16*)d_ws;
    __hip_bfloat16* lm = (__hip_bfloat16*)((char*)d_ws + (size_t)M * N_IN * 2);

    const int norm_blocks = M / 4;                 // 4096
    prep_kernel<<<norm_blocks + N_P, 256, 0, stream>>>(x, xn, lm_raw, lm, norm_blocks);

    const int nblk = (M / 256) * (N_P / 256);      // 64 * 4 = 256
    gemm_pair<<<nblk, dim3(512), 0, stream>>>(xn, lm, out, M, N_P, N_IN);
}